// Round 1
// baseline (78.709 us; speedup 1.0000x reference)
//
#include <hip/hip_runtime.h>

#define SEQ 512
#define MD  1024
#define RK  128

typedef __attribute__((ext_vector_type(8))) short  bf16x8;
typedef __attribute__((ext_vector_type(4))) float  floatx4;
typedef __attribute__((ext_vector_type(4))) unsigned int uint4v;
typedef __attribute__((ext_vector_type(4))) unsigned short ushortx4;

// RNE f32->bf16 (truncation measured too close to absmax threshold; RNE is free)
__device__ inline unsigned short f2bf(float f) {
    union { float f; unsigned u; } v; v.f = f;
    unsigned r = v.u + 0x7fffu + ((v.u >> 16) & 1u);
    return (unsigned short)(r >> 16);
}

// ---------- Kernel 0: PT[n][k] = bf16(proj[k][n]) ----------
// One-shot transpose+convert of the 512 KB proj so K1's B-fragments become
// contiguous b128 loads instead of 8 strided dword gathers + 8 f2bf each.
// 16384 threads; loads fully coalesced (lanes walk n), stores 16B segments
// (256 KB total -- negligible either way).
__global__ __launch_bounds__(256) void proj_t(
    const float* __restrict__ proj, unsigned short* __restrict__ PT)
{
    const int tid = blockIdx.x * 256 + threadIdx.x;
    const int n   = tid & 127;          // proj column = PT row
    const int kc  = (tid >> 7) * 8;     // 8 consecutive k per thread
    unsigned short tmp[8];
    #pragma unroll
    for (int j = 0; j < 8; ++j)
        tmp[j] = f2bf(proj[(size_t)(kc + j) * RK + n]);
    *(bf16x8*)(PT + (size_t)n * MD + kc) = *(bf16x8*)tmp;
}

// ---------- Kernel 1: T = bf16(batch @ proj) + row norms ----------
// 256 blocks x 512 threads (8 waves). Block owns 16 rows x full K.
// N (128 cols) split across waves: wave w -> cols [16w, 16w+16), full K=1024.
// => no cross-wave K-reduce, no 67KB Red buffer, one barrier.
// A tile converted to bf16 ONCE into LDS (33 KB); inner loop per thread is
// 32 x { ds_read_b128 (A) + global b128 (PT, L2-resident) + MFMA }.
#define LDA 1032   // bf16 row stride: 2064 B, /16B = 129 odd -> 2-way alias only

__global__ __launch_bounds__(512, 2) void proj_rows(
    const float* __restrict__ batch, const unsigned short* __restrict__ PT,
    unsigned short* __restrict__ T, float* __restrict__ Nrm)
{
    __shared__ unsigned short As[16 * LDA];   // 33 KB
    __shared__ float Np[8][16];               // per-wave row-norm partials

    const int t    = threadIdx.x;
    const int w    = t >> 6;
    const int l    = t & 63;
    const int lm   = l & 15;
    const int quad = l >> 4;
    const int r0   = blockIdx.x * 16;         // batch viewed as 4096 x 1024

    {   // stage A tile fp32 -> bf16: thread t -> row t>>5, 8-col chunks
        const int row = t >> 5, kb = (t & 31) * 8;
        const float* src = batch + (size_t)(r0 + row) * MD + kb;
        unsigned short* dst = As + row * LDA + kb;
        #pragma unroll
        for (int c = 0; c < 4; ++c) {         // chunks stride 256 floats
            float4 f0 = *(const float4*)(src + c * 256);
            float4 f1 = *(const float4*)(src + c * 256 + 4);
            unsigned short tmp[8];
            tmp[0] = f2bf(f0.x); tmp[1] = f2bf(f0.y);
            tmp[2] = f2bf(f0.z); tmp[3] = f2bf(f0.w);
            tmp[4] = f2bf(f1.x); tmp[5] = f2bf(f1.y);
            tmp[6] = f2bf(f1.z); tmp[7] = f2bf(f1.w);
            *(bf16x8*)(dst + c * 256) = *(bf16x8*)tmp;
        }
    }
    __syncthreads();

    // A frag: lane holds A[m=lm][k=s*32+quad*8+j]; B frag: PT[n=16w+lm][same k]
    floatx4 acc = (floatx4){0.f, 0.f, 0.f, 0.f};
    const unsigned short* aptr = As + lm * LDA + quad * 8;
    const unsigned short* bptr = PT + (size_t)(w * 16 + lm) * MD + quad * 8;

    #pragma unroll
    for (int s = 0; s < 32; ++s) {
        bf16x8 av = *(const bf16x8*)(aptr + s * 32);
        bf16x8 bv = *(const bf16x8*)(bptr + s * 32);
        acc = __builtin_amdgcn_mfma_f32_16x16x32_bf16(av, bv, acc, 0, 0, 0);
    }

    // D layout: row = quad*4+r (of 16 block rows), col = 16w+lm
    #pragma unroll
    for (int r = 0; r < 4; ++r) {
        float v = acc[r];
        T[(size_t)(r0 + quad * 4 + r) * RK + w * 16 + lm] = f2bf(v);
        // norm partial: sum v^2 over this wave's 16 cols (lm bits = lane bits 0..3)
        float p = v * v;
        p += __shfl_xor(p, 1, 64);
        p += __shfl_xor(p, 2, 64);
        p += __shfl_xor(p, 4, 64);
        p += __shfl_xor(p, 8, 64);
        if (lm == 0) Np[w][quad * 4 + r] = p;
    }
    __syncthreads();

    if (t < 16) {   // fold 8 wave partials -> row norm
        float s = 0.f;
        #pragma unroll
        for (int ww = 0; ww < 8; ++ww) s += Np[ww][t];
        Nrm[r0 + t] = s;
    }
}

// ---------- Kernel 2: D[b,i,j] = nI + nJ - 2 * (T_i . T_j), via MFMA ----------
// Grid (8 jt, 8 it, 8 b), 256 threads = 4 waves; 64x64 tile; wave w -> 16 i-rows.
#define LDB 136   // 128 + 8 bf16 pad: 16B rows, stride/16B odd -> 2-way alias only

__global__ __launch_bounds__(256) void dist_mfma(
    const unsigned short* __restrict__ T, const float* __restrict__ Nrm,
    float* __restrict__ out)
{
    __shared__ unsigned short Ti[64 * LDB];
    __shared__ unsigned short Tj[64 * LDB];
    __shared__ float nI[64], nJ[64];

    const int t    = threadIdx.x;
    const int w    = t >> 6;
    const int l    = t & 63;
    const int lm   = l & 15;
    const int quad = l >> 4;
    const int jt = blockIdx.x, it = blockIdx.y, b = blockIdx.z;
    const int i0 = it * 64, j0 = jt * 64;
    const unsigned short* Tb = T + (size_t)b * SEQ * RK;

    {   // stage both 64x128 bf16 tiles + norms
        int row = t >> 2, kq = (t & 3) * 32;
        const unsigned short* si = Tb + (size_t)(i0 + row) * RK + kq;
        const unsigned short* sj = Tb + (size_t)(j0 + row) * RK + kq;
        #pragma unroll
        for (int q = 0; q < 4; ++q) {
            *(uint4v*)(Ti + row * LDB + kq + q * 8) = *(const uint4v*)(si + q * 8);
            *(uint4v*)(Tj + row * LDB + kq + q * 8) = *(const uint4v*)(sj + q * 8);
        }
        if (t < 64)       nI[t]      = Nrm[(size_t)b * SEQ + i0 + t];
        else if (t < 128) nJ[t - 64] = Nrm[(size_t)b * SEQ + j0 + (t - 64)];
    }
    __syncthreads();

    floatx4 acc[4];
    #pragma unroll
    for (int i = 0; i < 4; ++i) acc[i] = (floatx4){0.f, 0.f, 0.f, 0.f};

    #pragma unroll
    for (int s = 0; s < 4; ++s) {
        bf16x8 av = *(const bf16x8*)(Ti + (w * 16 + lm) * LDB + s * 32 + quad * 8);
        #pragma unroll
        for (int nt = 0; nt < 4; ++nt) {
            bf16x8 bv = *(const bf16x8*)(Tj + (nt * 16 + lm) * LDB + s * 32 + quad * 8);
            acc[nt] = __builtin_amdgcn_mfma_f32_16x16x32_bf16(av, bv, acc[nt], 0, 0, 0);
        }
    }

    float niv[4];
    #pragma unroll
    for (int r = 0; r < 4; ++r) niv[r] = nI[w * 16 + quad * 4 + r];

    float* ob = out + ((size_t)b * SEQ + (i0 + w * 16)) * SEQ + j0;
    #pragma unroll
    for (int nt = 0; nt < 4; ++nt) {
        float njv = nJ[nt * 16 + lm];
        #pragma unroll
        for (int r = 0; r < 4; ++r) {
            ob[(size_t)(quad * 4 + r) * SEQ + nt * 16 + lm] =
                niv[r] + njv - 2.f * acc[nt][r];
        }
    }
}

extern "C" void kernel_launch(void* const* d_in, const int* in_sizes, int n_in,
                              void* d_out, int out_size, void* d_ws, size_t ws_size,
                              hipStream_t stream) {
    const float* batch = (const float*)d_in[0];   // (8, 512, 1024) fp32
    const float* proj  = (const float*)d_in[1];   // (1024, 128) fp32
    float* out = (float*)d_out;                   // (8, 512, 512) fp32

    unsigned short* T   = (unsigned short*)d_ws;                         // 1 MB bf16
    float*          Nrm = (float*)((char*)d_ws + (1 << 20));             // 16 KB fp32
    unsigned short* PT  = (unsigned short*)((char*)d_ws + (1 << 20) + (1 << 16)); // 256 KB bf16

    proj_t   <<<64,  256, 0, stream>>>(proj, PT);
    proj_rows<<<256, 512, 0, stream>>>(batch, PT, T, Nrm);
    dist_mfma<<<dim3(8, 8, 8), 256, 0, stream>>>(T, Nrm, out);
}